// Round 1
// baseline (289.065 us; speedup 1.0000x reference)
//
#include <hip/hip_runtime.h>
#include <math.h>

// Problem constants (from reference): B=8, Cin=Cout=64, H=W=96, K=3x3, stride=1, pad=1, dil=1
#define B_    8
#define CIN   64
#define COUT  64
#define H_    96
#define W_    96
#define HW    9216          // H_*W_
#define KK    9
#define PIX   64            // output pixels per block
#define NTHR  256
#define BLKS_PER_B 144      // HW / PIX

// One-time (per launch) weight transpose: wT[k][c][o] = weight[o][c][k]
// weight flat: o*576 + c*9 + k ; wT flat: k*4096 + c*64 + o
__global__ __launch_bounds__(256) void transpose_w_kernel(const float* __restrict__ w,
                                                          float* __restrict__ wT) {
    int idx = blockIdx.x * 256 + threadIdx.x;   // 0..36863
    int o = idx & 63;
    int c = (idx >> 6) & 63;
    int k = idx >> 12;
    wT[idx] = w[o * 576 + c * 9 + k];           // write coalesced, read gathered (tiny, one-shot)
}

// Main fused kernel.
// Block: 256 threads = 4 waves. lane = pixel (64 contiguous flattened hw), wave wq owns
// output channels wq*16..wq*16+15 -> 16 fp32 accumulators per thread.
// PRE=true: weights via wave-uniform scalar loads from transposed wT (s_load_dwordxN).
// PRE=false: fallback, scalar loads from original layout (correct, slower) if ws too small.
template <bool PRE>
__global__ __launch_bounds__(256, 4) void deform_main_kernel(
    const float* __restrict__ x, const float* __restrict__ offset,
    const float* __restrict__ x2, const float* __restrict__ weight,
    const float* __restrict__ bias, const float* __restrict__ wT,
    float* __restrict__ out)
{
    __shared__ float sT[CIN * PIX];      // 16 KB  sample tile s[c][p], stride 64
    __shared__ float ewS[4][KK * PIX];   // 9 KB   per-(k,p) masked bilinear corner weights
    __shared__ int   eoS[4][KK * PIX];   // 9 KB   per-(k,p) clamped corner offsets (y*W+x)

    const int tid  = threadIdx.x;
    const int b    = blockIdx.x / BLKS_PER_B;
    const int pix0 = (blockIdx.x % BLKS_PER_B) * PIX;
    const int lane = tid & 63;
    const int wq   = __builtin_amdgcn_readfirstlane(tid >> 6);  // 0..3, force scalar

    const float* xb   = x + b * (CIN * HW);
    const float* offb = offset + b * (18 * HW);

    // ---- precompute bilinear entries for the block's 64 pixels x 9 kernel taps ----
    for (int e = tid; e < KK * PIX; e += NTHR) {
        int k  = e >> 6;
        int p  = e & 63;
        int hw = pix0 + p;
        int h  = hw / W_;
        int w  = hw - h * W_;
        float offy = offb[(2 * k) * HW + hw];       // coalesced (lanes span p)
        float offx = offb[(2 * k + 1) * HW + hw];
        int ki = k / 3;
        int kj = k - ki * 3;
        float yy = (float)(h - 1 + ki) + offy;
        float xx = (float)(w - 1 + kj) + offx;
        float y0f = floorf(yy), x0f = floorf(xx);
        float wy1 = yy - y0f, wx1 = xx - x0f;
        float wy0 = 1.0f - wy1, wx0 = 1.0f - wx1;
        int y0 = (int)y0f, x0 = (int)x0f;
        int y1 = y0 + 1, x1 = x0 + 1;
        float vy0 = (y0 >= 0 && y0 < H_) ? 1.0f : 0.0f;
        float vy1 = (y1 >= 0 && y1 < H_) ? 1.0f : 0.0f;
        float vx0 = (x0 >= 0 && x0 < W_) ? 1.0f : 0.0f;
        float vx1 = (x1 >= 0 && x1 < W_) ? 1.0f : 0.0f;
        int y0c = min(max(y0, 0), H_ - 1), y1c = min(max(y1, 0), H_ - 1);
        int x0c = min(max(x0, 0), W_ - 1), x1c = min(max(x1, 0), W_ - 1);
        ewS[0][e] = wy0 * wx0 * vy0 * vx0;
        ewS[1][e] = wy0 * wx1 * vy0 * vx1;
        ewS[2][e] = wy1 * wx0 * vy1 * vx0;
        ewS[3][e] = wy1 * wx1 * vy1 * vx1;
        eoS[0][e] = y0c * W_ + x0c;
        eoS[1][e] = y0c * W_ + x1c;
        eoS[2][e] = y1c * W_ + x0c;
        eoS[3][e] = y1c * W_ + x1c;
    }

    float acc[16];
    #pragma unroll
    for (int i = 0; i < 16; ++i) acc[i] = 0.0f;

    __syncthreads();

    for (int k = 0; k < KK; ++k) {
        // ---- sampling: fill s[c][p] for this k. thread -> pixel=lane, c = cg*16 + i ----
        {
            const int eb = k * 64 + lane;
            const float w0 = ewS[0][eb], w1 = ewS[1][eb], w2 = ewS[2][eb], w3 = ewS[3][eb];
            const int   o0 = eoS[0][eb], o1 = eoS[1][eb], o2 = eoS[2][eb], o3 = eoS[3][eb];
            const int cg = tid >> 6;              // 0..3
            const float* xc = xb + (cg * 16) * HW;
            #pragma unroll
            for (int i = 0; i < 16; ++i) {
                float v = w0 * xc[o0] + w1 * xc[o1] + w2 * xc[o2] + w3 * xc[o3];
                sT[(cg * 16 + i) * 64 + lane] = v;   // conflict-free stride-64 write
                xc += HW;
            }
        }
        __syncthreads();

        // ---- compute: acc[oi] += w[wq*16+oi][c][k] * s[c][lane] ----
        if (PRE) {
            const float* wk = wT + k * 4096 + wq * 16;   // uniform -> scalar loads
            #pragma unroll 4
            for (int c = 0; c < 64; ++c) {
                float sv = sT[c * 64 + lane];            // coalesced ds_read_b32
                const float* wrow = wk + c * 64;
                #pragma unroll
                for (int oi = 0; oi < 16; ++oi)
                    acc[oi] = fmaf(wrow[oi], sv, acc[oi]);
            }
        } else {
            #pragma unroll 2
            for (int c = 0; c < 64; ++c) {
                float sv = sT[c * 64 + lane];
                #pragma unroll
                for (int oi = 0; oi < 16; ++oi)
                    acc[oi] = fmaf(weight[(wq * 16 + oi) * 576 + c * 9 + k], sv, acc[oi]);
            }
        }
        __syncthreads();   // protect sT before next k's sampling overwrites it
    }

    // ---- epilogue: + bias + x2, clip to [0,6], coalesced stores ----
    const int obase = (b * COUT + wq * 16) * HW + pix0 + lane;
    #pragma unroll
    for (int oi = 0; oi < 16; ++oi) {
        float r = acc[oi] + bias[wq * 16 + oi] + x2[obase + oi * HW];
        r = fminf(fmaxf(r, 0.0f), 6.0f);
        out[obase + oi * HW] = r;
    }
}

extern "C" void kernel_launch(void* const* d_in, const int* in_sizes, int n_in,
                              void* d_out, int out_size, void* d_ws, size_t ws_size,
                              hipStream_t stream) {
    const float* x      = (const float*)d_in[0];
    const float* offset = (const float*)d_in[1];
    const float* x2     = (const float*)d_in[2];
    const float* weight = (const float*)d_in[3];
    const float* bias   = (const float*)d_in[4];
    float* out          = (float*)d_out;

    const int grid = B_ * BLKS_PER_B;   // 1152 blocks

    if (ws_size >= (size_t)(COUT * CIN * KK) * sizeof(float)) {
        float* wT = (float*)d_ws;
        transpose_w_kernel<<<144, 256, 0, stream>>>(weight, wT);
        deform_main_kernel<true><<<grid, NTHR, 0, stream>>>(x, offset, x2, weight, bias, wT, out);
    } else {
        deform_main_kernel<false><<<grid, NTHR, 0, stream>>>(x, offset, x2, weight, bias, nullptr, out);
    }
}

// Round 2
// 217.895 us; speedup vs baseline: 1.3266x; 1.3266x over previous
//
#include <hip/hip_runtime.h>
#include <math.h>

// Problem constants: B=8, Cin=Cout=64, H=W=96, K=3x3, stride=1, pad=1, dil=1
#define B_    8
#define CIN   64
#define COUT  64
#define H_    96
#define W_    96
#define HW    9216          // H_*W_
#define KK    9
#define PIX   64            // output pixels per block
#define NTHR  256
#define BLKS_PER_B 144      // HW / PIX
#define ST    65            // padded stride for sT (avoid 64-way bank conflicts)

// ---------- one-time weight transpose: wT[k][c][o] = weight[o][c][k] ----------
__global__ __launch_bounds__(256) void transpose_w_kernel(const float* __restrict__ w,
                                                          float* __restrict__ wT) {
    int idx = blockIdx.x * 256 + threadIdx.x;   // 0..36863
    int o = idx & 63;
    int c = (idx >> 6) & 63;
    int k = idx >> 12;
    wT[idx] = w[o * 576 + c * 9 + k];
}

// ---------- NCHW -> NHWC transpose of x: xT[b][hw][c] = x[b][c][hw] ----------
// LDS-tiled so both global read and global write are coalesced.
__global__ __launch_bounds__(256) void nhwc_kernel(const float* __restrict__ x,
                                                   float* __restrict__ xT) {
    __shared__ float tile[64][ST];
    int b   = blockIdx.x / BLKS_PER_B;
    int hw0 = (blockIdx.x % BLKS_PER_B) * 64;
    int lane = threadIdx.x & 63;
    int r    = threadIdx.x >> 6;
    const float* xb = x + (size_t)b * CIN * HW;
    #pragma unroll
    for (int i = 0; i < 16; ++i) {
        int c = r + i * 4;
        tile[c][lane] = xb[(size_t)c * HW + hw0 + lane];   // coalesced read
    }
    __syncthreads();
    float* dst = xT + ((size_t)b * HW + hw0) * 64;
    #pragma unroll
    for (int i = 0; i < 16; ++i) {
        int p = r + i * 4;
        dst[(size_t)p * 64 + lane] = tile[lane][p];        // coalesced write, LDS conflict-free (pad)
    }
}

// ---------- main fused kernel (NHWC gather path) ----------
// Block: 256 threads = 4 waves, 64 contiguous output pixels of one batch.
// Sampling phase: lane = channel, wave wq handles pixels wq*16..+15 per tap ->
//   4 fully-coalesced 256B corner loads per (k,p), weights broadcast from LDS.
// Compute phase: lane = pixel, wave wq owns output channels wq*16..+15,
//   weights via wave-uniform scalar loads from wT.
// XCD swizzle: b = blockIdx & 7 pins each batch's x to one XCD's L2.
__global__ __launch_bounds__(256, 4) void deform_nhwc_kernel(
    const float* __restrict__ xT, const float* __restrict__ offset,
    const float* __restrict__ x2, const float* __restrict__ bias,
    const float* __restrict__ wT, float* __restrict__ out)
{
    __shared__ float  sT[CIN * ST];      // 16.6 KB  sample tile s[c][p], stride 65
    __shared__ float4 ew4[KK * PIX];     // 9.2 KB   packed masked bilinear corner weights
    __shared__ int4   eo4[KK * PIX];     // 9.2 KB   packed clamped corner positions (y*W+x)

    const int tid  = threadIdx.x;
    const int b    = blockIdx.x & 7;            // XCD-aware swizzle
    const int pix0 = (blockIdx.x >> 3) * PIX;
    const int lane = tid & 63;
    const int wq   = __builtin_amdgcn_readfirstlane(tid >> 6);

    const float* xTb  = xT + ((size_t)b * HW) * 64;
    const float* offb = offset + (size_t)b * (18 * HW);

    // ---- precompute bilinear entries for 64 pixels x 9 taps ----
    for (int e = tid; e < KK * PIX; e += NTHR) {
        int k  = e >> 6;
        int p  = e & 63;
        int hw = pix0 + p;
        int h  = hw / W_;
        int w  = hw - h * W_;
        float offy = offb[(size_t)(2 * k) * HW + hw];
        float offx = offb[(size_t)(2 * k + 1) * HW + hw];
        int ki = k / 3;
        int kj = k - ki * 3;
        float yy = (float)(h - 1 + ki) + offy;
        float xx = (float)(w - 1 + kj) + offx;
        float y0f = floorf(yy), x0f = floorf(xx);
        float wy1 = yy - y0f, wx1 = xx - x0f;
        float wy0 = 1.0f - wy1, wx0 = 1.0f - wx1;
        int y0 = (int)y0f, x0 = (int)x0f;
        int y1 = y0 + 1, x1 = x0 + 1;
        float vy0 = (y0 >= 0 && y0 < H_) ? 1.0f : 0.0f;
        float vy1 = (y1 >= 0 && y1 < H_) ? 1.0f : 0.0f;
        float vx0 = (x0 >= 0 && x0 < W_) ? 1.0f : 0.0f;
        float vx1 = (x1 >= 0 && x1 < W_) ? 1.0f : 0.0f;
        int y0c = min(max(y0, 0), H_ - 1), y1c = min(max(y1, 0), H_ - 1);
        int x0c = min(max(x0, 0), W_ - 1), x1c = min(max(x1, 0), W_ - 1);
        ew4[e] = make_float4(wy0 * wx0 * vy0 * vx0,
                             wy0 * wx1 * vy0 * vx1,
                             wy1 * wx0 * vy1 * vx0,
                             wy1 * wx1 * vy1 * vx1);
        eo4[e] = make_int4(y0c * W_ + x0c, y0c * W_ + x1c,
                           y1c * W_ + x0c, y1c * W_ + x1c);
    }

    float acc[16];
    #pragma unroll
    for (int i = 0; i < 16; ++i) acc[i] = 0.0f;

    __syncthreads();

    for (int k = 0; k < KK; ++k) {
        // ---- sampling: lane = channel; wave handles 16 pixels ----
        {
            const int pbase = wq * 16;
            #pragma unroll
            for (int j = 0; j < 16; ++j) {
                int e = k * 64 + pbase + j;
                float4 w4 = ew4[e];          // b128 broadcast
                int4   o4 = eo4[e];          // b128 broadcast
                float v;
                v = w4.x * xTb[((size_t)o4.x << 6) + lane];     // 256B coalesced
                v = fmaf(w4.y, xTb[((size_t)o4.y << 6) + lane], v);
                v = fmaf(w4.z, xTb[((size_t)o4.z << 6) + lane], v);
                v = fmaf(w4.w, xTb[((size_t)o4.w << 6) + lane], v);
                sT[lane * ST + pbase + j] = v;                  // conflict-free (pad 65)
            }
        }
        __syncthreads();

        // ---- compute: lane = pixel; acc[oi] += w[wq*16+oi][c][k] * s[c][lane] ----
        {
            const float* wk = wT + k * 4096 + wq * 16;   // wave-uniform -> s_load
            #pragma unroll 4
            for (int c = 0; c < 64; ++c) {
                float sv = sT[c * ST + lane];            // coalesced ds_read_b32
                const float* wrow = wk + c * 64;
                #pragma unroll
                for (int oi = 0; oi < 16; ++oi)
                    acc[oi] = fmaf(wrow[oi], sv, acc[oi]);
            }
        }
        __syncthreads();   // protect sT before next tap overwrites it
    }

    // ---- epilogue: + bias + x2, clip [0,6], coalesced stores ----
    const size_t obase = ((size_t)b * COUT + wq * 16) * HW + pix0 + lane;
    #pragma unroll
    for (int oi = 0; oi < 16; ++oi) {
        float r = acc[oi] + bias[wq * 16 + oi] + x2[obase + (size_t)oi * HW];
        r = fminf(fmaxf(r, 0.0f), 6.0f);
        out[obase + (size_t)oi * HW] = r;
    }
}

// ---------- fallback (round-1 NCHW gather path) if workspace too small ----------
__global__ __launch_bounds__(256, 4) void deform_nchw_kernel(
    const float* __restrict__ x, const float* __restrict__ offset,
    const float* __restrict__ x2, const float* __restrict__ weight,
    const float* __restrict__ bias, float* __restrict__ out)
{
    __shared__ float sT[CIN * PIX];
    __shared__ float ewS[4][KK * PIX];
    __shared__ int   eoS[4][KK * PIX];

    const int tid  = threadIdx.x;
    const int b    = blockIdx.x / BLKS_PER_B;
    const int pix0 = (blockIdx.x % BLKS_PER_B) * PIX;
    const int lane = tid & 63;
    const int wq   = __builtin_amdgcn_readfirstlane(tid >> 6);

    const float* xb   = x + (size_t)b * (CIN * HW);
    const float* offb = offset + (size_t)b * (18 * HW);

    for (int e = tid; e < KK * PIX; e += NTHR) {
        int k  = e >> 6;
        int p  = e & 63;
        int hw = pix0 + p;
        int h  = hw / W_;
        int w  = hw - h * W_;
        float offy = offb[(size_t)(2 * k) * HW + hw];
        float offx = offb[(size_t)(2 * k + 1) * HW + hw];
        int ki = k / 3;
        int kj = k - ki * 3;
        float yy = (float)(h - 1 + ki) + offy;
        float xx = (float)(w - 1 + kj) + offx;
        float y0f = floorf(yy), x0f = floorf(xx);
        float wy1 = yy - y0f, wx1 = xx - x0f;
        float wy0 = 1.0f - wy1, wx0 = 1.0f - wx1;
        int y0 = (int)y0f, x0 = (int)x0f;
        int y1 = y0 + 1, x1 = x0 + 1;
        float vy0 = (y0 >= 0 && y0 < H_) ? 1.0f : 0.0f;
        float vy1 = (y1 >= 0 && y1 < H_) ? 1.0f : 0.0f;
        float vx0 = (x0 >= 0 && x0 < W_) ? 1.0f : 0.0f;
        float vx1 = (x1 >= 0 && x1 < W_) ? 1.0f : 0.0f;
        int y0c = min(max(y0, 0), H_ - 1), y1c = min(max(y1, 0), H_ - 1);
        int x0c = min(max(x0, 0), W_ - 1), x1c = min(max(x1, 0), W_ - 1);
        ewS[0][e] = wy0 * wx0 * vy0 * vx0;
        ewS[1][e] = wy0 * wx1 * vy0 * vx1;
        ewS[2][e] = wy1 * wx0 * vy1 * vx0;
        ewS[3][e] = wy1 * wx1 * vy1 * vx1;
        eoS[0][e] = y0c * W_ + x0c;
        eoS[1][e] = y0c * W_ + x1c;
        eoS[2][e] = y1c * W_ + x0c;
        eoS[3][e] = y1c * W_ + x1c;
    }

    float acc[16];
    #pragma unroll
    for (int i = 0; i < 16; ++i) acc[i] = 0.0f;

    __syncthreads();

    for (int k = 0; k < KK; ++k) {
        {
            const int eb = k * 64 + lane;
            const float w0 = ewS[0][eb], w1 = ewS[1][eb], w2 = ewS[2][eb], w3 = ewS[3][eb];
            const int   o0 = eoS[0][eb], o1 = eoS[1][eb], o2 = eoS[2][eb], o3 = eoS[3][eb];
            const int cg = tid >> 6;
            const float* xc = xb + (size_t)(cg * 16) * HW;
            #pragma unroll
            for (int i = 0; i < 16; ++i) {
                float v = w0 * xc[o0] + w1 * xc[o1] + w2 * xc[o2] + w3 * xc[o3];
                sT[(cg * 16 + i) * 64 + lane] = v;
                xc += HW;
            }
        }
        __syncthreads();
        {
            #pragma unroll 2
            for (int c = 0; c < 64; ++c) {
                float sv = sT[c * 64 + lane];
                #pragma unroll
                for (int oi = 0; oi < 16; ++oi)
                    acc[oi] = fmaf(weight[(wq * 16 + oi) * 576 + c * 9 + k], sv, acc[oi]);
            }
        }
        __syncthreads();
    }

    const size_t obase = ((size_t)b * COUT + wq * 16) * HW + pix0 + lane;
    #pragma unroll
    for (int oi = 0; oi < 16; ++oi) {
        float r = acc[oi] + bias[wq * 16 + oi] + x2[obase + (size_t)oi * HW];
        r = fminf(fmaxf(r, 0.0f), 6.0f);
        out[obase + (size_t)oi * HW] = r;
    }
}

extern "C" void kernel_launch(void* const* d_in, const int* in_sizes, int n_in,
                              void* d_out, int out_size, void* d_ws, size_t ws_size,
                              hipStream_t stream) {
    const float* x      = (const float*)d_in[0];
    const float* offset = (const float*)d_in[1];
    const float* x2     = (const float*)d_in[2];
    const float* weight = (const float*)d_in[3];
    const float* bias   = (const float*)d_in[4];
    float* out          = (float*)d_out;

    const int grid = B_ * BLKS_PER_B;   // 1152 blocks

    const size_t xT_bytes = (size_t)B_ * HW * CIN * sizeof(float);      // 18.87 MB
    const size_t wT_bytes = (size_t)COUT * CIN * KK * sizeof(float);    // 147 KB

    if (ws_size >= xT_bytes + wT_bytes) {
        float* xT = (float*)d_ws;
        float* wT = (float*)((char*)d_ws + xT_bytes);
        transpose_w_kernel<<<144, 256, 0, stream>>>(weight, wT);
        nhwc_kernel<<<grid, 256, 0, stream>>>(x, xT);
        deform_nhwc_kernel<<<grid, NTHR, 0, stream>>>(xT, offset, x2, bias, wT, out);
    } else if (ws_size >= wT_bytes) {
        // no room for xT: fall back to NCHW gather with scalar weight loads
        deform_nchw_kernel<<<grid, NTHR, 0, stream>>>(x, offset, x2, weight, bias, out);
    } else {
        deform_nchw_kernel<<<grid, NTHR, 0, stream>>>(x, offset, x2, weight, bias, out);
    }
}

// Round 3
// 157.866 us; speedup vs baseline: 1.8311x; 1.3803x over previous
//
#include <hip/hip_runtime.h>
#include <math.h>

// Problem constants: B=8, Cin=Cout=64, H=W=96, K=3x3, stride=1, pad=1, dil=1
#define B_    8
#define CIN   64
#define COUT  64
#define H_    96
#define W_    96
#define HW    9216
#define KK    9
#define PIX   64            // output pixels per block
#define NTHR  256
#define BLKS_PER_B 144      // HW / PIX
#define SP    72            // S row stride in bf16 (64 + 8 pad, keeps 16B alignment)

typedef __attribute__((ext_vector_type(8))) short short8;
typedef __attribute__((ext_vector_type(4))) float floatx4;

static __device__ __forceinline__ unsigned short f2bf(float f) {
    unsigned u = __float_as_uint(f);
    unsigned r = (u + 0x7FFFu + ((u >> 16) & 1u)) >> 16;   // RNE
    return (unsigned short)r;
}
static __device__ __forceinline__ float bf_lo(unsigned u) { return __uint_as_float(u << 16); }
static __device__ __forceinline__ float bf_hi(unsigned u) { return __uint_as_float(u & 0xFFFF0000u); }

// ---------- prep 1: weights fp32 -> bf16 MFMA-A-fragment layout ----------
// wA frag row for (kstep κ∈[0,18), wq, lane): 8 bf16 at ((κ*4+wq)*64+lane)*8
// element j = W[o = wq*16 + (lane&15)][c = (κ&1)*32 + (lane>>4)*8 + j][tap = κ>>1]
__global__ __launch_bounds__(256) void prep_w_kernel(const float* __restrict__ w,
                                                     unsigned short* __restrict__ wA) {
    int gid  = blockIdx.x * 256 + threadIdx.x;   // [0, 4608)
    int lane = gid & 63;
    int wq   = (gid >> 6) & 3;
    int kap  = gid >> 8;                          // 0..17
    int o    = wq * 16 + (lane & 15);
    int cb   = (kap & 1) * 32 + (lane >> 4) * 8;
    int tap  = kap >> 1;
    short8 v;
    #pragma unroll
    for (int j = 0; j < 8; ++j)
        v[j] = (short)f2bf(w[o * 576 + (cb + j) * 9 + tap]);
    *(short8*)&wA[(size_t)gid * 8] = v;
}

// ---------- prep 2: x NCHW fp32 -> NHWC bf16 (channel pairs packed in uint) ----------
__global__ __launch_bounds__(256) void nhwc_bf16_kernel(const float* __restrict__ x,
                                                        unsigned int* __restrict__ xTu) {
    __shared__ float tile[64][65];
    int b   = blockIdx.x / BLKS_PER_B;
    int hw0 = (blockIdx.x % BLKS_PER_B) * 64;
    int lane = threadIdx.x & 63;
    int r    = threadIdx.x >> 6;
    const float* xb = x + (size_t)b * CIN * HW;
    #pragma unroll
    for (int i = 0; i < 16; ++i) {
        int c = r + i * 4;
        tile[c][lane] = xb[(size_t)c * HW + hw0 + lane];          // 256B coalesced
    }
    __syncthreads();
    unsigned int* dst = xTu + ((size_t)b * HW + hw0) * 32;
    int c2 = threadIdx.x & 31;
    int pr = threadIdx.x >> 5;          // 0..7
    #pragma unroll
    for (int i = 0; i < 8; ++i) {
        int p = pr + i * 8;
        unsigned pk = (unsigned)f2bf(tile[2 * c2][p]) |
                      ((unsigned)f2bf(tile[2 * c2 + 1][p]) << 16);
        dst[(size_t)p * 32 + c2] = pk;                            // 128B segments
    }
}

// ---------- main fused MFMA kernel ----------
// Block = 256 thr = 4 waves, 64 pixels x 64 out-channels of one batch.
// Wave wq: m-tile = out-channels [wq*16,+16), all 4 n-tiles (pixels).
// Per tap: sample bf16 NHWC -> S[p][c] (double-buffered), 1 barrier, 8 b128 + 8 MFMA.
__global__ __launch_bounds__(256, 4) void deform_mfma_kernel(
    const unsigned int* __restrict__ xTu, const float* __restrict__ offset,
    const float* __restrict__ x2, const float* __restrict__ bias,
    const unsigned short* __restrict__ wA, float* __restrict__ out)
{
    __shared__ float4 ew4[KK * PIX];                 // 9.2 KB
    __shared__ int4   eo4[KK * PIX];                 // 9.2 KB
    __shared__ __align__(16) short S[2][PIX * SP];   // 18.4 KB  (double-buffered sample tile)

    const int tid  = threadIdx.x;
    const int b    = blockIdx.x & 7;                 // XCD-friendly batch swizzle
    const int pix0 = (blockIdx.x >> 3) * PIX;
    const int lane = tid & 63;
    const int wq   = __builtin_amdgcn_readfirstlane(tid >> 6);

    const unsigned int* xb = xTu + (size_t)b * HW * 32;
    const float* offb = offset + (size_t)b * (18 * HW);

    // ---- preload all 18 A-fragments (weights, L2-resident, shared by all blocks) ----
    short8 afrag[18];
    {
        const short8* wAv = (const short8*)wA;
        #pragma unroll
        for (int kap = 0; kap < 18; ++kap)
            afrag[kap] = wAv[(size_t)(kap * 4 + wq) * 64 + lane];
    }

    // ---- precompute bilinear corner weights/positions for 64 px x 9 taps ----
    for (int e = tid; e < KK * PIX; e += NTHR) {
        int k  = e >> 6;
        int p  = e & 63;
        int hw = pix0 + p;
        int h  = hw / W_;
        int w  = hw - h * W_;
        float offy = offb[(size_t)(2 * k) * HW + hw];
        float offx = offb[(size_t)(2 * k + 1) * HW + hw];
        int ki = k / 3;
        int kj = k - ki * 3;
        float yy = (float)(h - 1 + ki) + offy;
        float xx = (float)(w - 1 + kj) + offx;
        float y0f = floorf(yy), x0f = floorf(xx);
        float wy1 = yy - y0f, wx1 = xx - x0f;
        float wy0 = 1.0f - wy1, wx0 = 1.0f - wx1;
        int y0 = (int)y0f, x0 = (int)x0f;
        int y1 = y0 + 1, x1 = x0 + 1;
        float vy0 = (y0 >= 0 && y0 < H_) ? 1.0f : 0.0f;
        float vy1 = (y1 >= 0 && y1 < H_) ? 1.0f : 0.0f;
        float vx0 = (x0 >= 0 && x0 < W_) ? 1.0f : 0.0f;
        float vx1 = (x1 >= 0 && x1 < W_) ? 1.0f : 0.0f;
        int y0c = min(max(y0, 0), H_ - 1), y1c = min(max(y1, 0), H_ - 1);
        int x0c = min(max(x0, 0), W_ - 1), x1c = min(max(x1, 0), W_ - 1);
        ew4[e] = make_float4(wy0 * wx0 * vy0 * vx0,
                             wy0 * wx1 * vy0 * vx1,
                             wy1 * wx0 * vy1 * vx0,
                             wy1 * wx1 * vy1 * vx1);
        eo4[e] = make_int4(y0c * W_ + x0c, y0c * W_ + x1c,
                           y1c * W_ + x0c, y1c * W_ + x1c);
    }

    floatx4 acc[4];
    #pragma unroll
    for (int nt = 0; nt < 4; ++nt) acc[nt] = (floatx4){0.f, 0.f, 0.f, 0.f};

    __syncthreads();

    const int c2   = lane & 31;     // channel-pair index (channels 2c2, 2c2+1)
    const int half = lane >> 5;     // 0/1: which of the pixel pair

    for (int t = 0; t < KK; ++t) {
        const int buf = t & 1;
        // ---- sampling: wave handles its 16 pixels as 8 pairs; lane = channel pair ----
        {
            unsigned int* Su = (unsigned int*)&S[buf][0];
            #pragma unroll
            for (int j = 0; j < 8; ++j) {
                int p = wq * 16 + j * 2 + half;
                int e = t * 64 + p;
                float4 w4 = ew4[e];          // LDS broadcast (2 addrs per wave)
                int4   o4 = eo4[e];
                unsigned u0 = xb[((size_t)o4.x << 5) + c2];   // 128B coalesced per half
                unsigned u1 = xb[((size_t)o4.y << 5) + c2];
                unsigned u2 = xb[((size_t)o4.z << 5) + c2];
                unsigned u3 = xb[((size_t)o4.w << 5) + c2];
                float vl = w4.x * bf_lo(u0);
                vl = fmaf(w4.y, bf_lo(u1), vl);
                vl = fmaf(w4.z, bf_lo(u2), vl);
                vl = fmaf(w4.w, bf_lo(u3), vl);
                float vh = w4.x * bf_hi(u0);
                vh = fmaf(w4.y, bf_hi(u1), vh);
                vh = fmaf(w4.z, bf_hi(u2), vh);
                vh = fmaf(w4.w, bf_hi(u3), vh);
                Su[p * (SP / 2) + c2] = (unsigned)f2bf(vl) | ((unsigned)f2bf(vh) << 16);
            }
        }
        __syncthreads();   // single barrier per tap (double-buffered S)

        // ---- MFMA: acc[nt] += A(weights) x B(samples) over this tap's 64 channels ----
        {
            const int n = lane & 15;
            const int qk = (lane >> 4) * 8;
            #pragma unroll
            for (int nt = 0; nt < 4; ++nt) {
                int p = nt * 16 + n;
                short8 b0 = *(const short8*)&S[buf][p * SP + qk];        // ds_read_b128
                short8 b1 = *(const short8*)&S[buf][p * SP + 32 + qk];
                acc[nt] = __builtin_amdgcn_mfma_f32_16x16x32_bf16(afrag[t * 2 + 0], b0, acc[nt], 0, 0, 0);
                acc[nt] = __builtin_amdgcn_mfma_f32_16x16x32_bf16(afrag[t * 2 + 1], b1, acc[nt], 0, 0, 0);
            }
        }
    }

    // ---- epilogue: + bias + x2, clip [0,6] ----
    // C/D layout: col = lane&15 (pixel), row = (lane>>4)*4 + reg (out channel)
    {
        const int n = lane & 15;
        const int orow = wq * 16 + (lane >> 4) * 4;
        float bia[4];
        #pragma unroll
        for (int reg = 0; reg < 4; ++reg) bia[reg] = bias[orow + reg];
        #pragma unroll
        for (int nt = 0; nt < 4; ++nt) {
            int hw = pix0 + nt * 16 + n;
            #pragma unroll
            for (int reg = 0; reg < 4; ++reg) {
                size_t idx = ((size_t)(b * COUT + orow + reg)) * HW + hw;
                float r = acc[nt][reg] + bia[reg] + x2[idx];
                r = fminf(fmaxf(r, 0.0f), 6.0f);
                out[idx] = r;
            }
        }
    }
}

// ---------- fallback (NCHW, fp32) if workspace too small ----------
__global__ __launch_bounds__(256, 4) void deform_nchw_kernel(
    const float* __restrict__ x, const float* __restrict__ offset,
    const float* __restrict__ x2, const float* __restrict__ weight,
    const float* __restrict__ bias, float* __restrict__ out)
{
    __shared__ float sT[CIN * PIX];
    __shared__ float ewS[4][KK * PIX];
    __shared__ int   eoS[4][KK * PIX];

    const int tid  = threadIdx.x;
    const int b    = blockIdx.x / BLKS_PER_B;
    const int pix0 = (blockIdx.x % BLKS_PER_B) * PIX;
    const int lane = tid & 63;
    const int wq   = __builtin_amdgcn_readfirstlane(tid >> 6);

    const float* xb   = x + (size_t)b * (CIN * HW);
    const float* offb = offset + (size_t)b * (18 * HW);

    for (int e = tid; e < KK * PIX; e += NTHR) {
        int k  = e >> 6;
        int p  = e & 63;
        int hw = pix0 + p;
        int h  = hw / W_;
        int w  = hw - h * W_;
        float offy = offb[(size_t)(2 * k) * HW + hw];
        float offx = offb[(size_t)(2 * k + 1) * HW + hw];
        int ki = k / 3;
        int kj = k - ki * 3;
        float yy = (float)(h - 1 + ki) + offy;
        float xx = (float)(w - 1 + kj) + offx;
        float y0f = floorf(yy), x0f = floorf(xx);
        float wy1 = yy - y0f, wx1 = xx - x0f;
        float wy0 = 1.0f - wy1, wx0 = 1.0f - wx1;
        int y0 = (int)y0f, x0 = (int)x0f;
        int y1 = y0 + 1, x1 = x0 + 1;
        float vy0 = (y0 >= 0 && y0 < H_) ? 1.0f : 0.0f;
        float vy1 = (y1 >= 0 && y1 < H_) ? 1.0f : 0.0f;
        float vx0 = (x0 >= 0 && x0 < W_) ? 1.0f : 0.0f;
        float vx1 = (x1 >= 0 && x1 < W_) ? 1.0f : 0.0f;
        int y0c = min(max(y0, 0), H_ - 1), y1c = min(max(y1, 0), H_ - 1);
        int x0c = min(max(x0, 0), W_ - 1), x1c = min(max(x1, 0), W_ - 1);
        ewS[0][e] = wy0 * wx0 * vy0 * vx0;
        ewS[1][e] = wy0 * wx1 * vy0 * vx1;
        ewS[2][e] = wy1 * wx0 * vy1 * vx0;
        ewS[3][e] = wy1 * wx1 * vy1 * vx1;
        eoS[0][e] = y0c * W_ + x0c;
        eoS[1][e] = y0c * W_ + x1c;
        eoS[2][e] = y1c * W_ + x0c;
        eoS[3][e] = y1c * W_ + x1c;
    }

    float acc[16];
    #pragma unroll
    for (int i = 0; i < 16; ++i) acc[i] = 0.0f;

    __syncthreads();

    for (int k = 0; k < KK; ++k) {
        {
            const int eb = k * 64 + lane;
            const float w0 = ewS[0][eb], w1 = ewS[1][eb], w2 = ewS[2][eb], w3 = ewS[3][eb];
            const int   o0 = eoS[0][eb], o1 = eoS[1][eb], o2 = eoS[2][eb], o3 = eoS[3][eb];
            const int cg = tid >> 6;
            const float* xc = xb + (size_t)(cg * 16) * HW;
            #pragma unroll
            for (int i = 0; i < 16; ++i) {
                float v = w0 * xc[o0] + w1 * xc[o1] + w2 * xc[o2] + w3 * xc[o3];
                sT[(cg * 16 + i) * 64 + lane] = v;
                xc += HW;
            }
        }
        __syncthreads();
        {
            #pragma unroll 2
            for (int c = 0; c < 64; ++c) {
                float sv = sT[c * 64 + lane];
                #pragma unroll
                for (int oi = 0; oi < 16; ++oi)
                    acc[oi] = fmaf(weight[(wq * 16 + oi) * 576 + c * 9 + k], sv, acc[oi]);
            }
        }
        __syncthreads();
    }

    const size_t obase = ((size_t)b * COUT + wq * 16) * HW + pix0 + lane;
    #pragma unroll
    for (int oi = 0; oi < 16; ++oi) {
        float r = acc[oi] + bias[wq * 16 + oi] + x2[obase + (size_t)oi * HW];
        r = fminf(fmaxf(r, 0.0f), 6.0f);
        out[obase + (size_t)oi * HW] = r;
    }
}

extern "C" void kernel_launch(void* const* d_in, const int* in_sizes, int n_in,
                              void* d_out, int out_size, void* d_ws, size_t ws_size,
                              hipStream_t stream) {
    const float* x      = (const float*)d_in[0];
    const float* offset = (const float*)d_in[1];
    const float* x2     = (const float*)d_in[2];
    const float* weight = (const float*)d_in[3];
    const float* bias   = (const float*)d_in[4];
    float* out          = (float*)d_out;

    const int grid = B_ * BLKS_PER_B;   // 1152 blocks

    const size_t xT_bytes = (size_t)B_ * HW * CIN * sizeof(unsigned short);  // 9.44 MB
    const size_t wA_bytes = (size_t)18 * 4 * 64 * 8 * sizeof(unsigned short); // 73.7 KB

    if (ws_size >= xT_bytes + wA_bytes) {
        unsigned int*   xTu = (unsigned int*)d_ws;
        unsigned short* wA  = (unsigned short*)((char*)d_ws + xT_bytes);
        prep_w_kernel<<<18, 256, 0, stream>>>(weight, wA);
        nhwc_bf16_kernel<<<grid, 256, 0, stream>>>(x, xTu);
        deform_mfma_kernel<<<grid, NTHR, 0, stream>>>(xTu, offset, x2, bias, wA, out);
    } else {
        deform_nchw_kernel<<<grid, NTHR, 0, stream>>>(x, offset, x2, weight, bias, out);
    }
}

// Round 4
// 134.978 us; speedup vs baseline: 2.1416x; 1.1696x over previous
//
#include <hip/hip_runtime.h>
#include <math.h>

// Problem constants: B=8, Cin=Cout=64, H=W=96, K=3x3, stride=1, pad=1, dil=1
#define B_    8
#define CIN   64
#define COUT  64
#define H_    96
#define W_    96
#define HW    9216
#define KK    9
#define PIX   64            // output pixels per block
#define NTHR  256
#define BLKS_PER_B 144      // HW / PIX
#define SP    72            // S row stride in bf16 (64 + 8 pad, keeps 16B alignment)

typedef __attribute__((ext_vector_type(8))) short short8;
typedef __attribute__((ext_vector_type(4))) float floatx4;

static __device__ __forceinline__ unsigned short f2bf(float f) {
    unsigned u = __float_as_uint(f);
    unsigned r = (u + 0x7FFFu + ((u >> 16) & 1u)) >> 16;   // RNE
    return (unsigned short)r;
}
static __device__ __forceinline__ float bf_lo(unsigned u) { return __uint_as_float(u << 16); }
static __device__ __forceinline__ float bf_hi(unsigned u) { return __uint_as_float(u & 0xFFFF0000u); }

// ---------- prep 1: weights fp32 -> bf16 MFMA-A-fragment layout ----------
// wA frag row for (kstep κ∈[0,18), wq, lane): 8 bf16 at ((κ*4+wq)*64+lane)*8
// element j = W[o = wq*16 + (lane&15)][c = (κ&1)*32 + (lane>>4)*8 + j][tap = κ>>1]
__global__ __launch_bounds__(256) void prep_w_kernel(const float* __restrict__ w,
                                                     unsigned short* __restrict__ wA) {
    int gid  = blockIdx.x * 256 + threadIdx.x;   // [0, 4608)
    int lane = gid & 63;
    int wq   = (gid >> 6) & 3;
    int kap  = gid >> 8;                          // 0..17
    int o    = wq * 16 + (lane & 15);
    int cb   = (kap & 1) * 32 + (lane >> 4) * 8;
    int tap  = kap >> 1;
    short8 v;
    #pragma unroll
    for (int j = 0; j < 8; ++j)
        v[j] = (short)f2bf(w[o * 576 + (cb + j) * 9 + tap]);
    *(short8*)&wA[(size_t)gid * 8] = v;
}

// ---------- prep 2: x NCHW fp32 -> NHWC bf16 (channel pairs packed in uint) ----------
__global__ __launch_bounds__(256) void nhwc_bf16_kernel(const float* __restrict__ x,
                                                        unsigned int* __restrict__ xTu) {
    __shared__ float tile[64][65];
    int b   = blockIdx.x / BLKS_PER_B;
    int hw0 = (blockIdx.x % BLKS_PER_B) * 64;
    int lane = threadIdx.x & 63;
    int r    = threadIdx.x >> 6;
    const float* xb = x + (size_t)b * CIN * HW;
    #pragma unroll
    for (int i = 0; i < 16; ++i) {
        int c = r + i * 4;
        tile[c][lane] = xb[(size_t)c * HW + hw0 + lane];          // 256B coalesced
    }
    __syncthreads();
    unsigned int* dst = xTu + ((size_t)b * HW + hw0) * 32;
    int c2 = threadIdx.x & 31;
    int pr = threadIdx.x >> 5;          // 0..7
    #pragma unroll
    for (int i = 0; i < 8; ++i) {
        int p = pr + i * 8;
        unsigned pk = (unsigned)f2bf(tile[2 * c2][p]) |
                      ((unsigned)f2bf(tile[2 * c2 + 1][p]) << 16);
        dst[(size_t)p * 32 + c2] = pk;                            // 128B segments
    }
}

// ---------- main fused MFMA kernel ----------
// Block = 256 thr = 4 waves, 64 pixels x 64 out-channels of one batch.
// Wave wq: m-tile = out-channels [wq*16,+16), all 4 n-tiles (pixels).
// Per tap: prefetch next tap's A-frags (global, L2-hot), sample bf16 NHWC ->
// S[p][c] (double-buffered), 1 barrier, 8 b128 + 8 MFMA with current A-frags.
// A-frags use a 2-tap register window (32 VGPRs) instead of all 18 (72 VGPRs,
// which spilled to scratch in R3: WRITE_SIZE 101 MB vs 19 MB output).
__global__ __launch_bounds__(256, 4) void deform_mfma_kernel(
    const unsigned int* __restrict__ xTu, const float* __restrict__ offset,
    const float* __restrict__ x2, const float* __restrict__ bias,
    const unsigned short* __restrict__ wA, float* __restrict__ out)
{
    __shared__ float4 ew4[KK * PIX];                 // 9.2 KB
    __shared__ int4   eo4[KK * PIX];                 // 9.2 KB
    __shared__ __align__(16) short S[2][PIX * SP];   // 18.4 KB  (double-buffered sample tile)

    const int tid  = threadIdx.x;
    const int b    = blockIdx.x & 7;                 // XCD-friendly batch swizzle
    const int pix0 = (blockIdx.x >> 3) * PIX;
    const int lane = tid & 63;
    const int wq   = __builtin_amdgcn_readfirstlane(tid >> 6);

    const unsigned int* xb = xTu + (size_t)b * HW * 32;
    const float* offb = offset + (size_t)b * (18 * HW);

    const short8* wAv = (const short8*)wA;
    const int abase = wq * 64 + lane;                // frag index for (kap=0, wq, lane)

    // ---- prime the 2-tap A-fragment window (tap 0: kap 0,1) ----
    short8 a0 = wAv[abase];                          // channels  0..31 of tap 0
    short8 a1 = wAv[abase + 4 * 64];                 // channels 32..63 of tap 0

    // ---- precompute bilinear corner weights/positions for 64 px x 9 taps ----
    for (int e = tid; e < KK * PIX; e += NTHR) {
        int k  = e >> 6;
        int p  = e & 63;
        int hw = pix0 + p;
        int h  = hw / W_;
        int w  = hw - h * W_;
        float offy = offb[(size_t)(2 * k) * HW + hw];
        float offx = offb[(size_t)(2 * k + 1) * HW + hw];
        int ki = k / 3;
        int kj = k - ki * 3;
        float yy = (float)(h - 1 + ki) + offy;
        float xx = (float)(w - 1 + kj) + offx;
        float y0f = floorf(yy), x0f = floorf(xx);
        float wy1 = yy - y0f, wx1 = xx - x0f;
        float wy0 = 1.0f - wy1, wx0 = 1.0f - wx1;
        int y0 = (int)y0f, x0 = (int)x0f;
        int y1 = y0 + 1, x1 = x0 + 1;
        float vy0 = (y0 >= 0 && y0 < H_) ? 1.0f : 0.0f;
        float vy1 = (y1 >= 0 && y1 < H_) ? 1.0f : 0.0f;
        float vx0 = (x0 >= 0 && x0 < W_) ? 1.0f : 0.0f;
        float vx1 = (x1 >= 0 && x1 < W_) ? 1.0f : 0.0f;
        int y0c = min(max(y0, 0), H_ - 1), y1c = min(max(y1, 0), H_ - 1);
        int x0c = min(max(x0, 0), W_ - 1), x1c = min(max(x1, 0), W_ - 1);
        ew4[e] = make_float4(wy0 * wx0 * vy0 * vx0,
                             wy0 * wx1 * vy0 * vx1,
                             wy1 * wx0 * vy1 * vx0,
                             wy1 * wx1 * vy1 * vx1);
        eo4[e] = make_int4(y0c * W_ + x0c, y0c * W_ + x1c,
                           y1c * W_ + x0c, y1c * W_ + x1c);
    }

    floatx4 acc[4];
    #pragma unroll
    for (int nt = 0; nt < 4; ++nt) acc[nt] = (floatx4){0.f, 0.f, 0.f, 0.f};

    __syncthreads();

    const int c2   = lane & 31;     // channel-pair index (channels 2c2, 2c2+1)
    const int half = lane >> 5;     // 0/1: which of the pixel pair

    for (int t = 0; t < KK; ++t) {
        const int buf = t & 1;

        // ---- prefetch next tap's A-frags (L2-hot, hides under sampler+barrier) ----
        short8 n0, n1;
        if (t < KK - 1) {
            n0 = wAv[abase + (8 * (t + 1)) * 64];
            n1 = wAv[abase + (8 * (t + 1) + 4) * 64];
        }

        // ---- sampling: wave handles its 16 pixels as 8 pairs; lane = channel pair ----
        {
            unsigned int* Su = (unsigned int*)&S[buf][0];
            #pragma unroll
            for (int j = 0; j < 8; ++j) {
                int p = wq * 16 + j * 2 + half;
                int e = t * 64 + p;
                float4 w4 = ew4[e];          // LDS broadcast (2 addrs per wave)
                int4   o4 = eo4[e];
                unsigned u0 = xb[((size_t)o4.x << 5) + c2];   // 128B coalesced per half
                unsigned u1 = xb[((size_t)o4.y << 5) + c2];
                unsigned u2 = xb[((size_t)o4.z << 5) + c2];
                unsigned u3 = xb[((size_t)o4.w << 5) + c2];
                float vl = w4.x * bf_lo(u0);
                vl = fmaf(w4.y, bf_lo(u1), vl);
                vl = fmaf(w4.z, bf_lo(u2), vl);
                vl = fmaf(w4.w, bf_lo(u3), vl);
                float vh = w4.x * bf_hi(u0);
                vh = fmaf(w4.y, bf_hi(u1), vh);
                vh = fmaf(w4.z, bf_hi(u2), vh);
                vh = fmaf(w4.w, bf_hi(u3), vh);
                Su[p * (SP / 2) + c2] = (unsigned)f2bf(vl) | ((unsigned)f2bf(vh) << 16);
            }
        }
        __syncthreads();   // single barrier per tap (double-buffered S)

        // ---- MFMA: acc[nt] += A(weights) x B(samples) over this tap's 64 channels ----
        {
            const int n = lane & 15;
            const int qk = (lane >> 4) * 8;
            #pragma unroll
            for (int nt = 0; nt < 4; ++nt) {
                int p = nt * 16 + n;
                short8 b0 = *(const short8*)&S[buf][p * SP + qk];        // ds_read_b128
                short8 b1 = *(const short8*)&S[buf][p * SP + 32 + qk];
                acc[nt] = __builtin_amdgcn_mfma_f32_16x16x32_bf16(a0, b0, acc[nt], 0, 0, 0);
                acc[nt] = __builtin_amdgcn_mfma_f32_16x16x32_bf16(a1, b1, acc[nt], 0, 0, 0);
            }
        }

        a0 = n0;   // slide the window
        a1 = n1;
    }

    // ---- epilogue: + bias + x2, clip [0,6] ----
    // C/D layout: col = lane&15 (pixel), row = (lane>>4)*4 + reg (out channel)
    {
        const int n = lane & 15;
        const int orow = wq * 16 + (lane >> 4) * 4;
        float bia[4];
        #pragma unroll
        for (int reg = 0; reg < 4; ++reg) bia[reg] = bias[orow + reg];
        #pragma unroll
        for (int nt = 0; nt < 4; ++nt) {
            int hw = pix0 + nt * 16 + n;
            #pragma unroll
            for (int reg = 0; reg < 4; ++reg) {
                size_t idx = ((size_t)(b * COUT + orow + reg)) * HW + hw;
                float r = acc[nt][reg] + bia[reg] + x2[idx];
                r = fminf(fmaxf(r, 0.0f), 6.0f);
                out[idx] = r;
            }
        }
    }
}

// ---------- fallback (NCHW, fp32) if workspace too small ----------
__global__ __launch_bounds__(256, 4) void deform_nchw_kernel(
    const float* __restrict__ x, const float* __restrict__ offset,
    const float* __restrict__ x2, const float* __restrict__ weight,
    const float* __restrict__ bias, float* __restrict__ out)
{
    __shared__ float sT[CIN * PIX];
    __shared__ float ewS[4][KK * PIX];
    __shared__ int   eoS[4][KK * PIX];

    const int tid  = threadIdx.x;
    const int b    = blockIdx.x / BLKS_PER_B;
    const int pix0 = (blockIdx.x % BLKS_PER_B) * PIX;
    const int lane = tid & 63;
    const int wq   = __builtin_amdgcn_readfirstlane(tid >> 6);

    const float* xb   = x + (size_t)b * (CIN * HW);
    const float* offb = offset + (size_t)b * (18 * HW);

    for (int e = tid; e < KK * PIX; e += NTHR) {
        int k  = e >> 6;
        int p  = e & 63;
        int hw = pix0 + p;
        int h  = hw / W_;
        int w  = hw - h * W_;
        float offy = offb[(size_t)(2 * k) * HW + hw];
        float offx = offb[(size_t)(2 * k + 1) * HW + hw];
        int ki = k / 3;
        int kj = k - ki * 3;
        float yy = (float)(h - 1 + ki) + offy;
        float xx = (float)(w - 1 + kj) + offx;
        float y0f = floorf(yy), x0f = floorf(xx);
        float wy1 = yy - y0f, wx1 = xx - x0f;
        float wy0 = 1.0f - wy1, wx0 = 1.0f - wx1;
        int y0 = (int)y0f, x0 = (int)x0f;
        int y1 = y0 + 1, x1 = x0 + 1;
        float vy0 = (y0 >= 0 && y0 < H_) ? 1.0f : 0.0f;
        float vy1 = (y1 >= 0 && y1 < H_) ? 1.0f : 0.0f;
        float vx0 = (x0 >= 0 && x0 < W_) ? 1.0f : 0.0f;
        float vx1 = (x1 >= 0 && x1 < W_) ? 1.0f : 0.0f;
        int y0c = min(max(y0, 0), H_ - 1), y1c = min(max(y1, 0), H_ - 1);
        int x0c = min(max(x0, 0), W_ - 1), x1c = min(max(x1, 0), W_ - 1);
        ewS[0][e] = wy0 * wx0 * vy0 * vx0;
        ewS[1][e] = wy0 * wx1 * vy0 * vx1;
        ewS[2][e] = wy1 * wx0 * vy1 * vx0;
        ewS[3][e] = wy1 * wx1 * vy1 * vx1;
        eoS[0][e] = y0c * W_ + x0c;
        eoS[1][e] = y0c * W_ + x1c;
        eoS[2][e] = y1c * W_ + x0c;
        eoS[3][e] = y1c * W_ + x1c;
    }

    float acc[16];
    #pragma unroll
    for (int i = 0; i < 16; ++i) acc[i] = 0.0f;

    __syncthreads();

    for (int k = 0; k < KK; ++k) {
        {
            const int eb = k * 64 + lane;
            const float w0 = ewS[0][eb], w1 = ewS[1][eb], w2 = ewS[2][eb], w3 = ewS[3][eb];
            const int   o0 = eoS[0][eb], o1 = eoS[1][eb], o2 = eoS[2][eb], o3 = eoS[3][eb];
            const int cg = tid >> 6;
            const float* xc = xb + (size_t)(cg * 16) * HW;
            #pragma unroll
            for (int i = 0; i < 16; ++i) {
                float v = w0 * xc[o0] + w1 * xc[o1] + w2 * xc[o2] + w3 * xc[o3];
                sT[(cg * 16 + i) * 64 + lane] = v;
                xc += HW;
            }
        }
        __syncthreads();
        {
            #pragma unroll 2
            for (int c = 0; c < 64; ++c) {
                float sv = sT[c * 64 + lane];
                #pragma unroll
                for (int oi = 0; oi < 16; ++oi)
                    acc[oi] = fmaf(weight[(wq * 16 + oi) * 576 + c * 9 + k], sv, acc[oi]);
            }
        }
        __syncthreads();
    }

    const size_t obase = ((size_t)b * COUT + wq * 16) * HW + pix0 + lane;
    #pragma unroll
    for (int oi = 0; oi < 16; ++oi) {
        float r = acc[oi] + bias[wq * 16 + oi] + x2[obase + (size_t)oi * HW];
        r = fminf(fmaxf(r, 0.0f), 6.0f);
        out[obase + (size_t)oi * HW] = r;
    }
}

extern "C" void kernel_launch(void* const* d_in, const int* in_sizes, int n_in,
                              void* d_out, int out_size, void* d_ws, size_t ws_size,
                              hipStream_t stream) {
    const float* x      = (const float*)d_in[0];
    const float* offset = (const float*)d_in[1];
    const float* x2     = (const float*)d_in[2];
    const float* weight = (const float*)d_in[3];
    const float* bias   = (const float*)d_in[4];
    float* out          = (float*)d_out;

    const int grid = B_ * BLKS_PER_B;   // 1152 blocks

    const size_t xT_bytes = (size_t)B_ * HW * CIN * sizeof(unsigned short);   // 9.44 MB
    const size_t wA_bytes = (size_t)18 * 4 * 64 * 8 * sizeof(unsigned short); // 73.7 KB

    if (ws_size >= xT_bytes + wA_bytes) {
        unsigned int*   xTu = (unsigned int*)d_ws;
        unsigned short* wA  = (unsigned short*)((char*)d_ws + xT_bytes);
        prep_w_kernel<<<18, 256, 0, stream>>>(weight, wA);
        nhwc_bf16_kernel<<<grid, 256, 0, stream>>>(x, xTu);
        deform_mfma_kernel<<<grid, NTHR, 0, stream>>>(xTu, offset, x2, bias, wA, out);
    } else {
        deform_nchw_kernel<<<grid, NTHR, 0, stream>>>(x, offset, x2, weight, bias, out);
    }
}

// Round 5
// 123.970 us; speedup vs baseline: 2.3317x; 1.0888x over previous
//
#include <hip/hip_runtime.h>
#include <math.h>

// Problem constants: B=8, Cin=Cout=64, H=W=96, K=3x3, stride=1, pad=1, dil=1
#define B_    8
#define CIN   64
#define COUT  64
#define H_    96
#define W_    96
#define HW    9216
#define KK    9
#define PIX   64            // output pixels per block
#define NTHR  256
#define BLKS_PER_B 144      // HW / PIX
#define SP    72            // S row stride in bf16 (144 B: 16B-aligned, 2-way-conflict-free)

typedef __attribute__((ext_vector_type(8))) short short8;
typedef __attribute__((ext_vector_type(4))) float floatx4;

static __device__ __forceinline__ unsigned short f2bf(float f) {
    unsigned u = __float_as_uint(f);
    unsigned r = (u + 0x7FFFu + ((u >> 16) & 1u)) >> 16;   // RNE
    return (unsigned short)r;
}
static __device__ __forceinline__ float bf_lo(unsigned u) { return __uint_as_float(u << 16); }
static __device__ __forceinline__ float bf_hi(unsigned u) { return __uint_as_float(u & 0xFFFF0000u); }

// ---------- merged prep: NCHW->NHWC bf16 transpose of x  +  weight->A-frag ----------
// blocks [0,1152): x transpose; blocks [1152,1170): weight prep.
// wA frag row for (kstep kap in [0,18), wq, lane): 8 bf16 at ((kap*4+wq)*64+lane)*8
// element j = W[o = wq*16 + (lane&15)][c = (kap&1)*32 + (lane>>4)*8 + j][tap = kap>>1]
__global__ __launch_bounds__(256) void prep_kernel(const float* __restrict__ x,
                                                   const float* __restrict__ w,
                                                   unsigned int* __restrict__ xTu,
                                                   unsigned short* __restrict__ wA) {
    __shared__ float tile[64][65];
    if (blockIdx.x < B_ * BLKS_PER_B) {
        int b   = blockIdx.x / BLKS_PER_B;
        int hw0 = (blockIdx.x % BLKS_PER_B) * 64;
        int lane = threadIdx.x & 63;
        int r    = threadIdx.x >> 6;
        const float* xb = x + (size_t)b * CIN * HW;
        #pragma unroll
        for (int i = 0; i < 16; ++i) {
            int c = r + i * 4;
            tile[c][lane] = xb[(size_t)c * HW + hw0 + lane];          // 256B coalesced
        }
        __syncthreads();
        unsigned int* dst = xTu + ((size_t)b * HW + hw0) * 32;
        int c2 = threadIdx.x & 31;
        int pr = threadIdx.x >> 5;          // 0..7
        #pragma unroll
        for (int i = 0; i < 8; ++i) {
            int p = pr + i * 8;
            unsigned pk = (unsigned)f2bf(tile[2 * c2][p]) |
                          ((unsigned)f2bf(tile[2 * c2 + 1][p]) << 16);
            dst[(size_t)p * 32 + c2] = pk;                            // 128B segments
        }
    } else {
        int gid  = (blockIdx.x - B_ * BLKS_PER_B) * 256 + threadIdx.x;   // [0, 4608)
        int lane = gid & 63;
        int wq   = (gid >> 6) & 3;
        int kap  = gid >> 8;                          // 0..17
        int o    = wq * 16 + (lane & 15);
        int cb   = (kap & 1) * 32 + (lane >> 4) * 8;
        int tap  = kap >> 1;
        short8 v;
        #pragma unroll
        for (int j = 0; j < 8; ++j)
            v[j] = (short)f2bf(w[o * 576 + (cb + j) * 9 + tap]);
        *(short8*)&wA[(size_t)gid * 8] = v;
    }
}

// ---- sampler helpers: load phase (32 hoisted gathers) / compute phase ----
static __device__ __forceinline__ void issue_tap_loads(
    const unsigned int* __restrict__ xb, const ushort4* eoS,
    int t, int wq, int half, int c2, unsigned u[8][4])
{
    #pragma unroll
    for (int j = 0; j < 8; ++j) {
        int p = wq * 16 + j * 2 + half;
        ushort4 o4 = eoS[t * 64 + p];                 // LDS broadcast (2 addrs/wave)
        u[j][0] = xb[((size_t)o4.x << 5) + c2];       // 128B coalesced per half-wave
        u[j][1] = xb[((size_t)o4.y << 5) + c2];
        u[j][2] = xb[((size_t)o4.z << 5) + c2];
        u[j][3] = xb[((size_t)o4.w << 5) + c2];
    }
}

static __device__ __forceinline__ void compute_tap(
    const uint2* awS, short* Sbuf, int t, int wq, int half, int c2,
    const unsigned u[8][4])
{
    unsigned int* Su = (unsigned int*)Sbuf;
    #pragma unroll
    for (int j = 0; j < 8; ++j) {
        int p = wq * 16 + j * 2 + half;
        uint2 aw = awS[t * 64 + p];                   // packed bf16 (ay0,ay1),(ax0,ax1)
        float ay0 = bf_lo(aw.x), ay1 = bf_hi(aw.x);
        float ax0 = bf_lo(aw.y), ax1 = bf_hi(aw.y);
        float w00 = ay0 * ax0, w01 = ay0 * ax1, w10 = ay1 * ax0, w11 = ay1 * ax1;
        float vl = w00 * bf_lo(u[j][0]);
        vl = fmaf(w01, bf_lo(u[j][1]), vl);
        vl = fmaf(w10, bf_lo(u[j][2]), vl);
        vl = fmaf(w11, bf_lo(u[j][3]), vl);
        float vh = w00 * bf_hi(u[j][0]);
        vh = fmaf(w01, bf_hi(u[j][1]), vh);
        vh = fmaf(w10, bf_hi(u[j][2]), vh);
        vh = fmaf(w11, bf_hi(u[j][3]), vh);
        Su[p * (SP / 2) + c2] = (unsigned)f2bf(vl) | ((unsigned)f2bf(vh) << 16);
    }
}

// ---------- main fused MFMA kernel ----------
// Block = 256 thr = 4 waves, 64 pixels x 64 out-channels of one batch.
// Per tap: [issue 32 hoisted corner loads] -> [bilinear, pack bf16 -> S (dbuf)]
// -> barrier -> [issue next tap's loads + A-frag prefetch, overlap 8 MFMA].
// LDS 27.6 KB (separable bf16 axis weights + ushort positions) -> up to 5 blk/CU.
__global__ __launch_bounds__(256, 4) void deform_mfma_kernel(
    const unsigned int* __restrict__ xTu, const float* __restrict__ offset,
    const float* __restrict__ x2, const float* __restrict__ bias,
    const unsigned short* __restrict__ wA, float* __restrict__ out)
{
    __shared__ uint2   awS[KK * PIX];                // 4.6 KB  axis weights (bf16 x4)
    __shared__ ushort4 eoS[KK * PIX];                // 4.6 KB  corner positions
    __shared__ __align__(16) short S[2][PIX * SP];   // 18.4 KB double-buffered sample tile

    const int tid  = threadIdx.x;
    const int b    = blockIdx.x & 7;                 // XCD-friendly batch swizzle
    const int pix0 = (blockIdx.x >> 3) * PIX;
    const int lane = tid & 63;
    const int wq   = __builtin_amdgcn_readfirstlane(tid >> 6);

    const unsigned int* xb = xTu + (size_t)b * HW * 32;
    const float* offb = offset + (size_t)b * (18 * HW);

    const short8* wAv = (const short8*)wA;
    const int abase = wq * 64 + lane;

    // prime tap-0 A-fragment window (L2-hot, shared by all blocks)
    short8 a0 = wAv[abase];                          // channels  0..31 of tap 0
    short8 a1 = wAv[abase + 4 * 64];                 // channels 32..63 of tap 0

    // ---- precompute separable masked bilinear entries for 64 px x 9 taps ----
    for (int e = tid; e < KK * PIX; e += NTHR) {
        int k  = e >> 6;
        int p  = e & 63;
        int hw = pix0 + p;
        int h  = hw / W_;
        int w  = hw - h * W_;
        float offy = offb[(size_t)(2 * k) * HW + hw];
        float offx = offb[(size_t)(2 * k + 1) * HW + hw];
        int ki = k / 3;
        int kj = k - ki * 3;
        float yy = (float)(h - 1 + ki) + offy;
        float xx = (float)(w - 1 + kj) + offx;
        float y0f = floorf(yy), x0f = floorf(xx);
        float wy1 = yy - y0f, wx1 = xx - x0f;
        float wy0 = 1.0f - wy1, wx0 = 1.0f - wx1;
        int y0 = (int)y0f, x0 = (int)x0f;
        int y1 = y0 + 1, x1 = x0 + 1;
        float ay0 = (y0 >= 0 && y0 < H_) ? wy0 : 0.0f;
        float ay1 = (y1 >= 0 && y1 < H_) ? wy1 : 0.0f;
        float ax0 = (x0 >= 0 && x0 < W_) ? wx0 : 0.0f;
        float ax1 = (x1 >= 0 && x1 < W_) ? wx1 : 0.0f;
        int y0c = min(max(y0, 0), H_ - 1), y1c = min(max(y1, 0), H_ - 1);
        int x0c = min(max(x0, 0), W_ - 1), x1c = min(max(x1, 0), W_ - 1);
        awS[e] = make_uint2((unsigned)f2bf(ay0) | ((unsigned)f2bf(ay1) << 16),
                            (unsigned)f2bf(ax0) | ((unsigned)f2bf(ax1) << 16));
        eoS[e] = make_ushort4((unsigned short)(y0c * W_ + x0c),
                              (unsigned short)(y0c * W_ + x1c),
                              (unsigned short)(y1c * W_ + x0c),
                              (unsigned short)(y1c * W_ + x1c));
    }

    floatx4 acc[4];
    #pragma unroll
    for (int nt = 0; nt < 4; ++nt) acc[nt] = (floatx4){0.f, 0.f, 0.f, 0.f};

    __syncthreads();

    const int c2   = lane & 31;     // channel-pair index (channels 2c2, 2c2+1)
    const int half = lane >> 5;     // 0/1: which pixel of the pair

    unsigned u[8][4];
    issue_tap_loads(xb, eoS, 0, wq, half, c2, u);

    for (int t = 0; t < KK; ++t) {
        const int buf = t & 1;

        compute_tap(awS, &S[buf][0], t, wq, half, c2, u);
        __syncthreads();   // single barrier per tap (double-buffered S)

        // overlap MFMA(t) with next tap's gathers + A-frag prefetch
        short8 n0, n1;
        if (t < KK - 1) {
            issue_tap_loads(xb, eoS, t + 1, wq, half, c2, u);
            n0 = wAv[abase + (8 * (t + 1)) * 64];
            n1 = wAv[abase + (8 * (t + 1) + 4) * 64];
        }

        {
            const int n = lane & 15;
            const int qk = (lane >> 4) * 8;
            #pragma unroll
            for (int nt = 0; nt < 4; ++nt) {
                int p = nt * 16 + n;
                short8 b0 = *(const short8*)&S[buf][p * SP + qk];        // ds_read_b128
                short8 b1 = *(const short8*)&S[buf][p * SP + 32 + qk];
                acc[nt] = __builtin_amdgcn_mfma_f32_16x16x32_bf16(a0, b0, acc[nt], 0, 0, 0);
                acc[nt] = __builtin_amdgcn_mfma_f32_16x16x32_bf16(a1, b1, acc[nt], 0, 0, 0);
            }
        }

        a0 = n0;   // slide the A window
        a1 = n1;
    }

    // ---- epilogue: + bias + x2, clip [0,6] ----
    // C/D layout: col = lane&15 (pixel), row = (lane>>4)*4 + reg (out channel)
    {
        const int n = lane & 15;
        const int orow = wq * 16 + (lane >> 4) * 4;
        float bia[4];
        #pragma unroll
        for (int reg = 0; reg < 4; ++reg) bia[reg] = bias[orow + reg];
        #pragma unroll
        for (int nt = 0; nt < 4; ++nt) {
            int hw = pix0 + nt * 16 + n;
            #pragma unroll
            for (int reg = 0; reg < 4; ++reg) {
                size_t idx = ((size_t)(b * COUT + orow + reg)) * HW + hw;
                float r = acc[nt][reg] + bia[reg] + x2[idx];
                r = fminf(fmaxf(r, 0.0f), 6.0f);
                out[idx] = r;
            }
        }
    }
}

// ---------- fallback (NCHW, fp32) if workspace too small ----------
__global__ __launch_bounds__(256, 4) void deform_nchw_kernel(
    const float* __restrict__ x, const float* __restrict__ offset,
    const float* __restrict__ x2, const float* __restrict__ weight,
    const float* __restrict__ bias, float* __restrict__ out)
{
    __shared__ float sT[CIN * PIX];
    __shared__ float ewS[4][KK * PIX];
    __shared__ int   eoS[4][KK * PIX];

    const int tid  = threadIdx.x;
    const int b    = blockIdx.x / BLKS_PER_B;
    const int pix0 = (blockIdx.x % BLKS_PER_B) * PIX;
    const int lane = tid & 63;
    const int wq   = __builtin_amdgcn_readfirstlane(tid >> 6);

    const float* xb   = x + (size_t)b * (CIN * HW);
    const float* offb = offset + (size_t)b * (18 * HW);

    for (int e = tid; e < KK * PIX; e += NTHR) {
        int k  = e >> 6;
        int p  = e & 63;
        int hw = pix0 + p;
        int h  = hw / W_;
        int w  = hw - h * W_;
        float offy = offb[(size_t)(2 * k) * HW + hw];
        float offx = offb[(size_t)(2 * k + 1) * HW + hw];
        int ki = k / 3;
        int kj = k - ki * 3;
        float yy = (float)(h - 1 + ki) + offy;
        float xx = (float)(w - 1 + kj) + offx;
        float y0f = floorf(yy), x0f = floorf(xx);
        float wy1 = yy - y0f, wx1 = xx - x0f;
        float wy0 = 1.0f - wy1, wx0 = 1.0f - wx1;
        int y0 = (int)y0f, x0 = (int)x0f;
        int y1 = y0 + 1, x1 = x0 + 1;
        float vy0 = (y0 >= 0 && y0 < H_) ? 1.0f : 0.0f;
        float vy1 = (y1 >= 0 && y1 < H_) ? 1.0f : 0.0f;
        float vx0 = (x0 >= 0 && x0 < W_) ? 1.0f : 0.0f;
        float vx1 = (x1 >= 0 && x1 < W_) ? 1.0f : 0.0f;
        int y0c = min(max(y0, 0), H_ - 1), y1c = min(max(y1, 0), H_ - 1);
        int x0c = min(max(x0, 0), W_ - 1), x1c = min(max(x1, 0), W_ - 1);
        ewS[0][e] = wy0 * wx0 * vy0 * vx0;
        ewS[1][e] = wy0 * wx1 * vy0 * vx1;
        ewS[2][e] = wy1 * wx0 * vy1 * vx0;
        ewS[3][e] = wy1 * wx1 * vy1 * vx1;
        eoS[0][e] = y0c * W_ + x0c;
        eoS[1][e] = y0c * W_ + x1c;
        eoS[2][e] = y1c * W_ + x0c;
        eoS[3][e] = y1c * W_ + x1c;
    }

    float acc[16];
    #pragma unroll
    for (int i = 0; i < 16; ++i) acc[i] = 0.0f;

    __syncthreads();

    for (int k = 0; k < KK; ++k) {
        {
            const int eb = k * 64 + lane;
            const float w0 = ewS[0][eb], w1 = ewS[1][eb], w2 = ewS[2][eb], w3 = ewS[3][eb];
            const int   o0 = eoS[0][eb], o1 = eoS[1][eb], o2 = eoS[2][eb], o3 = eoS[3][eb];
            const int cg = tid >> 6;
            const float* xc = xb + (size_t)(cg * 16) * HW;
            #pragma unroll
            for (int i = 0; i < 16; ++i) {
                float v = w0 * xc[o0] + w1 * xc[o1] + w2 * xc[o2] + w3 * xc[o3];
                sT[(cg * 16 + i) * 64 + lane] = v;
                xc += HW;
            }
        }
        __syncthreads();
        {
            #pragma unroll 2
            for (int c = 0; c < 64; ++c) {
                float sv = sT[c * 64 + lane];
                #pragma unroll
                for (int oi = 0; oi < 16; ++oi)
                    acc[oi] = fmaf(weight[(wq * 16 + oi) * 576 + c * 9 + k], sv, acc[oi]);
            }
        }
        __syncthreads();
    }

    const size_t obase = ((size_t)b * COUT + wq * 16) * HW + pix0 + lane;
    #pragma unroll
    for (int oi = 0; oi < 16; ++oi) {
        float r = acc[oi] + bias[wq * 16 + oi] + x2[obase + (size_t)oi * HW];
        r = fminf(fmaxf(r, 0.0f), 6.0f);
        out[obase + (size_t)oi * HW] = r;
    }
}

extern "C" void kernel_launch(void* const* d_in, const int* in_sizes, int n_in,
                              void* d_out, int out_size, void* d_ws, size_t ws_size,
                              hipStream_t stream) {
    const float* x      = (const float*)d_in[0];
    const float* offset = (const float*)d_in[1];
    const float* x2     = (const float*)d_in[2];
    const float* weight = (const float*)d_in[3];
    const float* bias   = (const float*)d_in[4];
    float* out          = (float*)d_out;

    const int grid = B_ * BLKS_PER_B;   // 1152 blocks

    const size_t xT_bytes = (size_t)B_ * HW * CIN * sizeof(unsigned short);   // 9.44 MB
    const size_t wA_bytes = (size_t)18 * 4 * 64 * 8 * sizeof(unsigned short); // 73.7 KB

    if (ws_size >= xT_bytes + wA_bytes) {
        unsigned int*   xTu = (unsigned int*)d_ws;
        unsigned short* wA  = (unsigned short*)((char*)d_ws + xT_bytes);
        prep_kernel<<<grid + 18, 256, 0, stream>>>(x, weight, xTu, wA);
        deform_mfma_kernel<<<grid, NTHR, 0, stream>>>(xTu, offset, x2, bias, wA, out);
    } else {
        deform_nchw_kernel<<<grid, NTHR, 0, stream>>>(x, offset, x2, weight, bias, out);
    }
}

// Round 6
// 117.980 us; speedup vs baseline: 2.4501x; 1.0508x over previous
//
#include <hip/hip_runtime.h>
#include <math.h>

// Problem constants: B=8, Cin=Cout=64, H=W=96, K=3x3, stride=1, pad=1, dil=1
#define B_    8
#define CIN   64
#define COUT  64
#define H_    96
#define W_    96
#define HW    9216
#define KK    9
#define PIX   64            // output pixels per block
#define NTHR  256
#define BLKS_PER_B 144      // HW / PIX
#define SP    72            // S row stride in bf16 (144 B: 16B-aligned, 2-way-conflict-free)

typedef __attribute__((ext_vector_type(8))) short short8;
typedef __attribute__((ext_vector_type(4))) float floatx4;

#if __has_builtin(__builtin_amdgcn_fdot2_f32_bf16)
#define HAVE_DOT2 1
typedef __attribute__((ext_vector_type(2))) __bf16 bf16x2;
static __device__ __forceinline__ bf16x2 as_bf16x2(unsigned u) {
    union { unsigned u; bf16x2 v; } c; c.u = u; return c.v;
}
#else
#define HAVE_DOT2 0
#endif

static __device__ __forceinline__ unsigned short f2bf(float f) {
    unsigned u = __float_as_uint(f);
    unsigned r = (u + 0x7FFFu + ((u >> 16) & 1u)) >> 16;   // RNE
    return (unsigned short)r;
}
static __device__ __forceinline__ float bf_lo(unsigned u) { return __uint_as_float(u << 16); }
static __device__ __forceinline__ float bf_hi(unsigned u) { return __uint_as_float(u & 0xFFFF0000u); }

// cheap bf16x2 pack: round-half-away (+0x8000) then splice high halves with one v_perm
static __device__ __forceinline__ unsigned pack_bf2(float vl, float vh) {
    unsigned rl = __float_as_uint(vl) + 0x8000u;
    unsigned rh = __float_as_uint(vh) + 0x8000u;
    return __builtin_amdgcn_perm(rh, rl, 0x07060302u);   // (hi16(rh)<<16)|hi16(rl)
}

// ---------- merged prep: NCHW->NHWC bf16 transpose of x  +  weight->A-frag ----------
// blocks [0,1152): x transpose; blocks [1152,1170): weight prep.
// wA frag row for (kstep kap in [0,18), wq, lane): 8 bf16 at ((kap*4+wq)*64+lane)*8
// element j = W[o = wq*16 + (lane&15)][c = (kap&1)*32 + (lane>>4)*8 + j][tap = kap>>1]
__global__ __launch_bounds__(256) void prep_kernel(const float* __restrict__ x,
                                                   const float* __restrict__ w,
                                                   unsigned int* __restrict__ xTu,
                                                   unsigned short* __restrict__ wA) {
    __shared__ float tile[64][65];
    if (blockIdx.x < B_ * BLKS_PER_B) {
        int b   = blockIdx.x / BLKS_PER_B;
        int hw0 = (blockIdx.x % BLKS_PER_B) * 64;
        int lane = threadIdx.x & 63;
        int r    = threadIdx.x >> 6;
        const float* xb = x + (size_t)b * CIN * HW;
        #pragma unroll
        for (int i = 0; i < 16; ++i) {
            int c = r + i * 4;
            tile[c][lane] = xb[(size_t)c * HW + hw0 + lane];          // 256B coalesced
        }
        __syncthreads();
        unsigned int* dst = xTu + ((size_t)b * HW + hw0) * 32;
        int c2 = threadIdx.x & 31;
        int pr = threadIdx.x >> 5;          // 0..7
        #pragma unroll
        for (int i = 0; i < 8; ++i) {
            int p = pr + i * 8;
            unsigned pk = (unsigned)f2bf(tile[2 * c2][p]) |
                          ((unsigned)f2bf(tile[2 * c2 + 1][p]) << 16);
            dst[(size_t)p * 32 + c2] = pk;                            // 128B segments
        }
    } else {
        int gid  = (blockIdx.x - B_ * BLKS_PER_B) * 256 + threadIdx.x;   // [0, 4608)
        int lane = gid & 63;
        int wq   = (gid >> 6) & 3;
        int kap  = gid >> 8;                          // 0..17
        int o    = wq * 16 + (lane & 15);
        int cb   = (kap & 1) * 32 + (lane >> 4) * 8;
        int tap  = kap >> 1;
        short8 v;
        #pragma unroll
        for (int j = 0; j < 8; ++j)
            v[j] = (short)f2bf(w[o * 576 + (cb + j) * 9 + tap]);
        *(short8*)&wA[(size_t)gid * 8] = v;
    }
}

// ---- sampler helpers: load phase (32 hoisted gathers) / compute phase ----
static __device__ __forceinline__ void issue_tap_loads(
    const unsigned int* __restrict__ xb, const ushort4* eoS,
    int t, int wq, int half, int c2, unsigned u[8][4])
{
    #pragma unroll
    for (int j = 0; j < 8; ++j) {
        int p = wq * 16 + j * 2 + half;
        ushort4 o4 = eoS[t * 64 + p];                 // LDS broadcast (2 addrs/wave)
        u[j][0] = xb[((size_t)o4.x << 5) + c2];       // 128B coalesced per half-wave
        u[j][1] = xb[((size_t)o4.y << 5) + c2];
        u[j][2] = xb[((size_t)o4.z << 5) + c2];
        u[j][3] = xb[((size_t)o4.w << 5) + c2];
    }
}

#if HAVE_DOT2
// products packed as bf16 pairs: awP[e] = { (w00,w01), (w10,w11) }
static __device__ __forceinline__ void compute_tap(
    const uint2* awP, short* Sbuf, int t, int wq, int half, int c2,
    const unsigned u[8][4])
{
    unsigned int* Su = (unsigned int*)Sbuf;
    #pragma unroll
    for (int j = 0; j < 8; ++j) {
        int p = wq * 16 + j * 2 + half;
        uint2 aw = awP[t * 64 + p];                    // ds_read_b64 broadcast
        // repack corner pairs per channel with v_perm
        unsigned lo01 = __builtin_amdgcn_perm(u[j][1], u[j][0], 0x05040100u);
        unsigned hi01 = __builtin_amdgcn_perm(u[j][1], u[j][0], 0x07060302u);
        unsigned lo23 = __builtin_amdgcn_perm(u[j][3], u[j][2], 0x05040100u);
        unsigned hi23 = __builtin_amdgcn_perm(u[j][3], u[j][2], 0x07060302u);
        float vl = __builtin_amdgcn_fdot2_f32_bf16(as_bf16x2(lo01), as_bf16x2(aw.x), 0.0f, false);
        vl = __builtin_amdgcn_fdot2_f32_bf16(as_bf16x2(lo23), as_bf16x2(aw.y), vl, false);
        float vh = __builtin_amdgcn_fdot2_f32_bf16(as_bf16x2(hi01), as_bf16x2(aw.x), 0.0f, false);
        vh = __builtin_amdgcn_fdot2_f32_bf16(as_bf16x2(hi23), as_bf16x2(aw.y), vh, false);
        Su[p * (SP / 2) + c2] = pack_bf2(vl, vh);
    }
}
#else
// products stored as float4 (w00,w01,w10,w11)
static __device__ __forceinline__ void compute_tap(
    const float4* ewP, short* Sbuf, int t, int wq, int half, int c2,
    const unsigned u[8][4])
{
    unsigned int* Su = (unsigned int*)Sbuf;
    #pragma unroll
    for (int j = 0; j < 8; ++j) {
        int p = wq * 16 + j * 2 + half;
        float4 w4 = ewP[t * 64 + p];                   // ds_read_b128 broadcast
        float vl = w4.x * bf_lo(u[j][0]);
        vl = fmaf(w4.y, bf_lo(u[j][1]), vl);
        vl = fmaf(w4.z, bf_lo(u[j][2]), vl);
        vl = fmaf(w4.w, bf_lo(u[j][3]), vl);
        float vh = w4.x * bf_hi(u[j][0]);
        vh = fmaf(w4.y, bf_hi(u[j][1]), vh);
        vh = fmaf(w4.z, bf_hi(u[j][2]), vh);
        vh = fmaf(w4.w, bf_hi(u[j][3]), vh);
        Su[p * (SP / 2) + c2] = pack_bf2(vl, vh);
    }
}
#endif

// ---------- main fused MFMA kernel ----------
// Block = 256 thr = 4 waves, 64 pixels x 64 out-channels of one batch.
// Per tap: [bilinear via perm+dot2 (or fma), cheap pack -> S (dbuf)] -> barrier ->
// [issue next tap's 32 hoisted gathers + A-frag prefetch, overlap 8 MFMA].
__global__ __launch_bounds__(256, 4) void deform_mfma_kernel(
    const unsigned int* __restrict__ xTu, const float* __restrict__ offset,
    const float* __restrict__ x2, const float* __restrict__ bias,
    const unsigned short* __restrict__ wA, float* __restrict__ out)
{
#if HAVE_DOT2
    __shared__ uint2   awP[KK * PIX];                // 4.6 KB  packed bf16 corner products
#else
    __shared__ float4  awP[KK * PIX];                // 9.2 KB  f32 corner products
#endif
    __shared__ ushort4 eoS[KK * PIX];                // 4.6 KB  corner positions
    __shared__ __align__(16) short S[2][PIX * SP];   // 18.4 KB double-buffered sample tile

    const int tid  = threadIdx.x;
    const int b    = blockIdx.x & 7;                 // XCD-friendly batch swizzle
    const int pix0 = (blockIdx.x >> 3) * PIX;
    const int lane = tid & 63;
    const int wq   = __builtin_amdgcn_readfirstlane(tid >> 6);

    const unsigned int* xb = xTu + (size_t)b * HW * 32;
    const float* offb = offset + (size_t)b * (18 * HW);

    const short8* wAv = (const short8*)wA;
    const int abase = wq * 64 + lane;

    // prime tap-0 A-fragment window (L2-hot, shared by all blocks)
    short8 a0 = wAv[abase];                          // channels  0..31 of tap 0
    short8 a1 = wAv[abase + 4 * 64];                 // channels 32..63 of tap 0

    // ---- precompute masked bilinear corner products for 64 px x 9 taps ----
    for (int e = tid; e < KK * PIX; e += NTHR) {
        int k  = e >> 6;
        int p  = e & 63;
        int hw = pix0 + p;
        int h  = hw / W_;
        int w  = hw - h * W_;
        float offy = offb[(size_t)(2 * k) * HW + hw];
        float offx = offb[(size_t)(2 * k + 1) * HW + hw];
        int ki = k / 3;
        int kj = k - ki * 3;
        float yy = (float)(h - 1 + ki) + offy;
        float xx = (float)(w - 1 + kj) + offx;
        float y0f = floorf(yy), x0f = floorf(xx);
        float wy1 = yy - y0f, wx1 = xx - x0f;
        float wy0 = 1.0f - wy1, wx0 = 1.0f - wx1;
        int y0 = (int)y0f, x0 = (int)x0f;
        int y1 = y0 + 1, x1 = x0 + 1;
        float ay0 = (y0 >= 0 && y0 < H_) ? wy0 : 0.0f;
        float ay1 = (y1 >= 0 && y1 < H_) ? wy1 : 0.0f;
        float ax0 = (x0 >= 0 && x0 < W_) ? wx0 : 0.0f;
        float ax1 = (x1 >= 0 && x1 < W_) ? wx1 : 0.0f;
        float w00 = ay0 * ax0, w01 = ay0 * ax1, w10 = ay1 * ax0, w11 = ay1 * ax1;
        int y0c = min(max(y0, 0), H_ - 1), y1c = min(max(y1, 0), H_ - 1);
        int x0c = min(max(x0, 0), W_ - 1), x1c = min(max(x1, 0), W_ - 1);
#if HAVE_DOT2
        awP[e] = make_uint2((unsigned)f2bf(w00) | ((unsigned)f2bf(w01) << 16),
                            (unsigned)f2bf(w10) | ((unsigned)f2bf(w11) << 16));
#else
        awP[e] = make_float4(w00, w01, w10, w11);
#endif
        eoS[e] = make_ushort4((unsigned short)(y0c * W_ + x0c),
                              (unsigned short)(y0c * W_ + x1c),
                              (unsigned short)(y1c * W_ + x0c),
                              (unsigned short)(y1c * W_ + x1c));
    }

    floatx4 acc[4];
    #pragma unroll
    for (int nt = 0; nt < 4; ++nt) acc[nt] = (floatx4){0.f, 0.f, 0.f, 0.f};

    __syncthreads();

    const int c2   = lane & 31;     // channel-pair index (channels 2c2, 2c2+1)
    const int half = lane >> 5;     // 0/1: which pixel of the pair

    unsigned u[8][4];
    issue_tap_loads(xb, eoS, 0, wq, half, c2, u);

    for (int t = 0; t < KK; ++t) {
        const int buf = t & 1;

        compute_tap(awP, &S[buf][0], t, wq, half, c2, u);
        __syncthreads();   // single barrier per tap (double-buffered S)

        // overlap MFMA(t) with next tap's gathers + A-frag prefetch
        short8 n0, n1;
        if (t < KK - 1) {
            issue_tap_loads(xb, eoS, t + 1, wq, half, c2, u);
            n0 = wAv[abase + (8 * (t + 1)) * 64];
            n1 = wAv[abase + (8 * (t + 1) + 4) * 64];
        }

        {
            const int n = lane & 15;
            const int qk = (lane >> 4) * 8;
            #pragma unroll
            for (int nt = 0; nt < 4; ++nt) {
                int p = nt * 16 + n;
                short8 b0 = *(const short8*)&S[buf][p * SP + qk];        // ds_read_b128
                short8 b1 = *(const short8*)&S[buf][p * SP + 32 + qk];
                acc[nt] = __builtin_amdgcn_mfma_f32_16x16x32_bf16(a0, b0, acc[nt], 0, 0, 0);
                acc[nt] = __builtin_amdgcn_mfma_f32_16x16x32_bf16(a1, b1, acc[nt], 0, 0, 0);
            }
        }

        a0 = n0;   // slide the A window
        a1 = n1;
    }

    // ---- epilogue: + bias + x2, clip [0,6] ----
    // C/D layout: col = lane&15 (pixel), row = (lane>>4)*4 + reg (out channel)
    {
        const int n = lane & 15;
        const int orow = wq * 16 + (lane >> 4) * 4;
        float bia[4];
        #pragma unroll
        for (int reg = 0; reg < 4; ++reg) bia[reg] = bias[orow + reg];
        #pragma unroll
        for (int nt = 0; nt < 4; ++nt) {
            int hw = pix0 + nt * 16 + n;
            #pragma unroll
            for (int reg = 0; reg < 4; ++reg) {
                size_t idx = ((size_t)(b * COUT + orow + reg)) * HW + hw;
                float r = acc[nt][reg] + bia[reg] + x2[idx];
                r = fminf(fmaxf(r, 0.0f), 6.0f);
                out[idx] = r;
            }
        }
    }
}

// ---------- fallback (NCHW, fp32) if workspace too small ----------
__global__ __launch_bounds__(256, 4) void deform_nchw_kernel(
    const float* __restrict__ x, const float* __restrict__ offset,
    const float* __restrict__ x2, const float* __restrict__ weight,
    const float* __restrict__ bias, float* __restrict__ out)
{
    __shared__ float sT[CIN * PIX];
    __shared__ float ewS[4][KK * PIX];
    __shared__ int   eoS[4][KK * PIX];

    const int tid  = threadIdx.x;
    const int b    = blockIdx.x / BLKS_PER_B;
    const int pix0 = (blockIdx.x % BLKS_PER_B) * PIX;
    const int lane = tid & 63;
    const int wq   = __builtin_amdgcn_readfirstlane(tid >> 6);

    const float* xb   = x + (size_t)b * (CIN * HW);
    const float* offb = offset + (size_t)b * (18 * HW);

    for (int e = tid; e < KK * PIX; e += NTHR) {
        int k  = e >> 6;
        int p  = e & 63;
        int hw = pix0 + p;
        int h  = hw / W_;
        int w  = hw - h * W_;
        float offy = offb[(size_t)(2 * k) * HW + hw];
        float offx = offb[(size_t)(2 * k + 1) * HW + hw];
        int ki = k / 3;
        int kj = k - ki * 3;
        float yy = (float)(h - 1 + ki) + offy;
        float xx = (float)(w - 1 + kj) + offx;
        float y0f = floorf(yy), x0f = floorf(xx);
        float wy1 = yy - y0f, wx1 = xx - x0f;
        float wy0 = 1.0f - wy1, wx0 = 1.0f - wx1;
        int y0 = (int)y0f, x0 = (int)x0f;
        int y1 = y0 + 1, x1 = x0 + 1;
        float vy0 = (y0 >= 0 && y0 < H_) ? 1.0f : 0.0f;
        float vy1 = (y1 >= 0 && y1 < H_) ? 1.0f : 0.0f;
        float vx0 = (x0 >= 0 && x0 < W_) ? 1.0f : 0.0f;
        float vx1 = (x1 >= 0 && x1 < W_) ? 1.0f : 0.0f;
        int y0c = min(max(y0, 0), H_ - 1), y1c = min(max(y1, 0), H_ - 1);
        int x0c = min(max(x0, 0), W_ - 1), x1c = min(max(x1, 0), W_ - 1);
        ewS[0][e] = wy0 * wx0 * vy0 * vx0;
        ewS[1][e] = wy0 * wx1 * vy0 * vx1;
        ewS[2][e] = wy1 * wx0 * vy1 * vx0;
        ewS[3][e] = wy1 * wx1 * vy1 * vx1;
        eoS[0][e] = y0c * W_ + x0c;
        eoS[1][e] = y0c * W_ + x1c;
        eoS[2][e] = y1c * W_ + x0c;
        eoS[3][e] = y1c * W_ + x1c;
    }

    float acc[16];
    #pragma unroll
    for (int i = 0; i < 16; ++i) acc[i] = 0.0f;

    __syncthreads();

    for (int k = 0; k < KK; ++k) {
        {
            const int eb = k * 64 + lane;
            const float w0 = ewS[0][eb], w1 = ewS[1][eb], w2 = ewS[2][eb], w3 = ewS[3][eb];
            const int   o0 = eoS[0][eb], o1 = eoS[1][eb], o2 = eoS[2][eb], o3 = eoS[3][eb];
            const int cg = tid >> 6;
            const float* xc = xb + (size_t)(cg * 16) * HW;
            #pragma unroll
            for (int i = 0; i < 16; ++i) {
                float v = w0 * xc[o0] + w1 * xc[o1] + w2 * xc[o2] + w3 * xc[o3];
                sT[(cg * 16 + i) * 64 + lane] = v;
                xc += HW;
            }
        }
        __syncthreads();
        {
            #pragma unroll 2
            for (int c = 0; c < 64; ++c) {
                float sv = sT[c * 64 + lane];
                #pragma unroll
                for (int oi = 0; oi < 16; ++oi)
                    acc[oi] = fmaf(weight[(wq * 16 + oi) * 576 + c * 9 + k], sv, acc[oi]);
            }
        }
        __syncthreads();
    }

    const size_t obase = ((size_t)b * COUT + wq * 16) * HW + pix0 + lane;
    #pragma unroll
    for (int oi = 0; oi < 16; ++oi) {
        float r = acc[oi] + bias[wq * 16 + oi] + x2[obase + (size_t)oi * HW];
        r = fminf(fmaxf(r, 0.0f), 6.0f);
        out[obase + (size_t)oi * HW] = r;
    }
}

extern "C" void kernel_launch(void* const* d_in, const int* in_sizes, int n_in,
                              void* d_out, int out_size, void* d_ws, size_t ws_size,
                              hipStream_t stream) {
    const float* x      = (const float*)d_in[0];
    const float* offset = (const float*)d_in[1];
    const float* x2     = (const float*)d_in[2];
    const float* weight = (const float*)d_in[3];
    const float* bias   = (const float*)d_in[4];
    float* out          = (float*)d_out;

    const int grid = B_ * BLKS_PER_B;   // 1152 blocks

    const size_t xT_bytes = (size_t)B_ * HW * CIN * sizeof(unsigned short);   // 9.44 MB
    const size_t wA_bytes = (size_t)18 * 4 * 64 * 8 * sizeof(unsigned short); // 73.7 KB

    if (ws_size >= xT_bytes + wA_bytes) {
        unsigned int*   xTu = (unsigned int*)d_ws;
        unsigned short* wA  = (unsigned short*)((char*)d_ws + xT_bytes);
        prep_kernel<<<grid + 18, 256, 0, stream>>>(x, weight, xTu, wA);
        deform_mfma_kernel<<<grid, NTHR, 0, stream>>>(xTu, offset, x2, bias, wA, out);
    } else {
        deform_nchw_kernel<<<grid, NTHR, 0, stream>>>(x, offset, x2, weight, bias, out);
    }
}